// Round 5
// baseline (259.735 us; speedup 1.0000x reference)
//
#include <hip/hip_runtime.h>
#include <hip/hip_bf16.h>

// Problem constants (B=4, T=2048, D=1024, H=16, HD=64)
constexpr int NB  = 4;
constexpr int NT  = 2048;
constexpr int ND  = 1024;
constexpr int NH  = 16;
constexpr int NHD = 64;
constexpr int NM  = NB * NT;   // 8192 tokens

typedef unsigned short u16;
typedef __attribute__((ext_vector_type(8))) short  short8;  // 8 bf16 (4 VGPRs)
typedef __attribute__((ext_vector_type(4))) float  f32x4;   // MFMA acc

__device__ __forceinline__ u16 f2bf(float f) {
  unsigned u = __builtin_bit_cast(unsigned, f);
  u += 0x7FFFu + ((u >> 16) & 1u);   // round-to-nearest-even
  return (u16)(u >> 16);
}

// pack two f32 -> 2x bf16 in one dword (compiler emits v_cvt_pk_bf16_f32)
__device__ __forceinline__ unsigned pk2bf(float lo, float hi_) {
  float2 t; t.x = lo; t.y = hi_;
  __hip_bfloat162 h2 = __float22bfloat162_rn(t);
  unsigned u;
  __builtin_memcpy(&u, &h2, 4);
  return u;
}

// async global->LDS, 16B per lane. dst must be wave-uniform; lane i lands at dst + i*16B.
__device__ __forceinline__ void gll16(const u16* src, u16* dst) {
  __builtin_amdgcn_global_load_lds(
      (const __attribute__((address_space(1))) void*)src,
      (__attribute__((address_space(3))) void*)dst, 16, 0, 0);
}

// ---------------- cast f32 -> bf16, vectorized x4 ----------------
__global__ __launch_bounds__(256) void cast_kernel(const float* __restrict__ in,
                                                   u16* __restrict__ out, int n4) {
  int i = blockIdx.x * 256 + threadIdx.x;
  if (i >= n4) return;
  float4 v = ((const float4*)in)[i];
  ushort4 o;
  o.x = f2bf(v.x); o.y = f2bf(v.y); o.z = f2bf(v.z); o.w = f2bf(v.w);
  ((ushort4*)out)[i] = o;
}

// ---------------- QKV GEMM: y = x @ W^T ----------------
// Q,K scattered to [B,H,T,HD] (swapped-orientation MFMA: rg = 4 consecutive d -> uint2 store);
// V scattered TRANSPOSED to [B,H,HD,T] (normal orientation: rg = 4 consecutive t -> uint2 store).
__global__ __launch_bounds__(256) void gemm_qkv(
    const u16* __restrict__ xb,
    const u16* __restrict__ wqb, const u16* __restrict__ wkb, const u16* __restrict__ wvb,
    u16* __restrict__ Qb, u16* __restrict__ Kb, u16* __restrict__ VTb) {
  const int z = blockIdx.z;
  const u16* wsel = (z == 0) ? wqb : (z == 1) ? wkb : wvb;
  u16* osel      = (z == 0) ? Qb  : (z == 1) ? Kb  : VTb;
  // attention scale + log2(e) folded into Q (softmax done in exp2 domain)
  const float scl = (z == 0) ? 0.125f * 1.44269504f : 1.0f;

  const int row0 = blockIdx.x * 128;
  const int col0 = blockIdx.y * 128;
  const int tid  = threadIdx.x;
  const int lane = tid & 63, wid = tid >> 6;
  const int wm = wid >> 1, wn = wid & 1;
  const int li = lane & 15, hi = lane >> 4;

  __shared__ __align__(16) u16 lA[128 * 32];
  __shared__ __align__(16) u16 lB[128 * 32];

  f32x4 acc[4][4] = {};
  const int rl = lane >> 2;   // 0..15 (row within 16-row slab)
  const int c8 = lane & 3;    // 8-elem chunk within 32-elem row

  for (int k0 = 0; k0 < ND; k0 += 32) {
#pragma unroll
    for (int h = 0; h < 2; ++h) {
      int r = wid * 32 + h * 16 + rl;
      gll16(&xb  [(size_t)(row0 + r) * ND + k0 + c8 * 8], &lA[(wid * 32 + h * 16) * 32]);
      gll16(&wsel[(size_t)(col0 + r) * ND + k0 + c8 * 8], &lB[(wid * 32 + h * 16) * 32]);
    }
    __syncthreads();
    short8 a[4], b[4];
#pragma unroll
    for (int m = 0; m < 4; ++m)
      a[m] = *(const short8*)&lA[(wm * 64 + m * 16 + li) * 32 + hi * 8];
#pragma unroll
    for (int n = 0; n < 4; ++n)
      b[n] = *(const short8*)&lB[(wn * 64 + n * 16 + li) * 32 + hi * 8];
    if (z == 2) {
#pragma unroll
      for (int m = 0; m < 4; ++m)
#pragma unroll
        for (int n = 0; n < 4; ++n)
          acc[m][n] = __builtin_amdgcn_mfma_f32_16x16x32_bf16(a[m], b[n], acc[m][n], 0, 0, 0);
    } else {  // swapped: acc = C^T fragment (row=feature, col=token)
#pragma unroll
      for (int m = 0; m < 4; ++m)
#pragma unroll
        for (int n = 0; n < 4; ++n)
          acc[m][n] = __builtin_amdgcn_mfma_f32_16x16x32_bf16(b[n], a[m], acc[m][n], 0, 0, 0);
    }
    __syncthreads();
  }

#pragma unroll
  for (int m = 0; m < 4; ++m)
#pragma unroll
    for (int n = 0; n < 4; ++n) {
      if (z == 2) {
        // normal: row=token(hi*4+rg), col=feature(li). Pack 4 consecutive t.
        int token0 = row0 + wm * 64 + m * 16 + hi * 4;
        int col    = col0 + wn * 64 + n * 16 + li;
        int b_ = token0 >> 11, t0 = token0 & (NT - 1);
        int h_ = col >> 6,     d_ = col & (NHD - 1);
        uint2 w;
        w.x = pk2bf(acc[m][n][0], acc[m][n][1]);
        w.y = pk2bf(acc[m][n][2], acc[m][n][3]);
        *(uint2*)&osel[(((size_t)(b_ * NH + h_)) * NHD + d_) * NT + t0] = w;
      } else {
        // swapped: row=feature(hi*4+rg), col=token(li). Pack 4 consecutive d.
        int token = row0 + wm * 64 + m * 16 + li;
        int feat0 = col0 + wn * 64 + n * 16 + hi * 4;
        int b_ = token >> 11, t_ = token & (NT - 1);
        int h_ = feat0 >> 6,  d0 = feat0 & (NHD - 1);
        uint2 w;
        w.x = pk2bf(acc[m][n][0] * scl, acc[m][n][1] * scl);
        w.y = pk2bf(acc[m][n][2] * scl, acc[m][n][3] * scl);
        *(uint2*)&osel[(((size_t)(b_ * NH + h_)) * NT + t_) * NHD + d0] = w;
      }
    }
}

// ---------------- WO GEMM + residual: out = x + AO @ WO^T (f32 out) ----------------
// Swapped orientation: rg = 4 consecutive features -> float4 load/store.
__global__ __launch_bounds__(256) void gemm_wo(
    const u16* __restrict__ ao, const u16* __restrict__ wob,
    const float* __restrict__ x, float* __restrict__ y) {
  const int row0 = blockIdx.x * 128;
  const int col0 = blockIdx.y * 128;
  const int tid  = threadIdx.x;
  const int lane = tid & 63, wid = tid >> 6;
  const int wm = wid >> 1, wn = wid & 1;
  const int li = lane & 15, hi = lane >> 4;

  __shared__ __align__(16) u16 lA[128 * 32];
  __shared__ __align__(16) u16 lB[128 * 32];

  f32x4 acc[4][4] = {};
  const int rl = lane >> 2;
  const int c8 = lane & 3;

  for (int k0 = 0; k0 < ND; k0 += 32) {
#pragma unroll
    for (int h = 0; h < 2; ++h) {
      int r = wid * 32 + h * 16 + rl;
      gll16(&ao [(size_t)(row0 + r) * ND + k0 + c8 * 8], &lA[(wid * 32 + h * 16) * 32]);
      gll16(&wob[(size_t)(col0 + r) * ND + k0 + c8 * 8], &lB[(wid * 32 + h * 16) * 32]);
    }
    __syncthreads();
    short8 a[4], b[4];
#pragma unroll
    for (int m = 0; m < 4; ++m)
      a[m] = *(const short8*)&lA[(wm * 64 + m * 16 + li) * 32 + hi * 8];
#pragma unroll
    for (int n = 0; n < 4; ++n)
      b[n] = *(const short8*)&lB[(wn * 64 + n * 16 + li) * 32 + hi * 8];
#pragma unroll
    for (int m = 0; m < 4; ++m)
#pragma unroll
      for (int n = 0; n < 4; ++n)
        acc[m][n] = __builtin_amdgcn_mfma_f32_16x16x32_bf16(b[n], a[m], acc[m][n], 0, 0, 0);
    __syncthreads();
  }

#pragma unroll
  for (int m = 0; m < 4; ++m)
#pragma unroll
    for (int n = 0; n < 4; ++n) {
      int token = row0 + wm * 64 + m * 16 + li;
      int feat0 = col0 + wn * 64 + n * 16 + hi * 4;
      size_t idx = (size_t)token * ND + feat0;
      float4 xv = *(const float4*)&x[idx];
      float4 o;
      o.x = acc[m][n][0] + xv.x; o.y = acc[m][n][1] + xv.y;
      o.z = acc[m][n][2] + xv.z; o.w = acc[m][n][3] + xv.w;
      *(float4*)&y[idx] = o;
    }
}

// ---------------- causal flash attention (swapped softmax, 32 q/wave, ones-trick rowsum) ----
// grid 1024 blocks (16 q-supertiles x 64 bh), XCD-swizzled. 4 waves; wave owns 32 q-rows
// as two 16-row groups sharing the K/V LDS fragments.
// S = mfma(K, Q): lane holds S[q=li][k=g*16+hi*4+rg]. O = mfma(V^T, P). Rowsum via
// o4 = mfma(ones, P) accumulator (rescaled with O on defer-max events).
__global__ __launch_bounds__(256) void attn_kernel(
    const u16* __restrict__ Q, const u16* __restrict__ K, const u16* __restrict__ VT,
    u16* __restrict__ AO) {
  // T1: XCD-aware swizzle (1024 % 8 == 0 -> bijective)
  const int nb  = gridDim.x * gridDim.y;           // 1024
  const int b0  = blockIdx.y * gridDim.x + blockIdx.x;
  const int L   = (b0 & 7) * (nb >> 3) + (b0 >> 3);
  const int qs  = L & 15;            // q super-tile (128 rows)
  const int bh  = L >> 4;            // 0..63

  const int tid = threadIdx.x;
  const int lane = tid & 63, wid = tid >> 6;
  const int li = lane & 15, hi = lane >> 4;
  const int r0 = qs * 128 + wid * 32;        // wave's 32 q rows
  const size_t bK = (size_t)bh * NT * NHD;   // K  [bh][t][d]
  const size_t bV = (size_t)bh * NHD * NT;   // VT [bh][d][t]

  __shared__ __align__(16) u16 lK [2][64 * 64];
  __shared__ __align__(16) u16 lVT[2][64 * 64];
  __shared__ __align__(16) u16 lP [4][2][16 * 64];

  const int rl = lane >> 3;   // 0..7
  const int sl = lane & 7;    // dest chunk slot

  // Q fragments (B-operand): lane holds Q[r0+grp*16+li][c*32 + hi*8 + e]
  short8 qf[2][2];
#pragma unroll
  for (int grp = 0; grp < 2; ++grp)
#pragma unroll
    for (int c = 0; c < 2; ++c)
      qf[grp][c] = *(const short8*)&Q[bK + (size_t)(r0 + grp * 16 + li) * NHD + c * 32 + hi * 8];

  short8 vone;
#pragma unroll
  for (int e = 0; e < 8; ++e) vone[e] = (short)0x3F80;   // bf16 1.0

  f32x4 o[2][4] = {};
  f32x4 o4[2] = {};                    // rowsum accumulators (all regs equal)
  float mr[2] = {-INFINITY, -INFINITY};

  // ---- stage tile kt into buffer buf (pre-swizzled source, linear LDS dest) ----
  auto stage = [&](int buf, int kt) {
#pragma unroll
    for (int h = 0; h < 2; ++h) {
      int r  = wid * 16 + h * 8 + rl;        // tile row 0..63
      int c8 = sl ^ (r & 7);                 // source chunk for this dest slot
      gll16(&K [bK + (size_t)(kt * 64 + r) * NHD + c8 * 8], &lK [buf][(wid * 16 + h * 8) * 64]);
      gll16(&VT[bV + (size_t)r * NT + kt * 64 + c8 * 8],    &lVT[buf][(wid * 16 + h * 8) * 64]);
    }
  };

  const int nkt = 2 * qs + 2;
  stage(0, 0);
  __syncthreads();
  int buf = 0;

  const int pswz = (li & 7) << 1;   // P-LDS XOR swizzle (8B chunks, bit0 preserved)

  for (int kt = 0; kt < nkt; ++kt) {
    if (kt + 1 < nkt) stage(buf ^ 1, kt + 1);     // issue next tile before compute

    if (kt * 64 <= r0 + 31) {                     // wave-uniform: skip fully-masked tiles
      // S^T = K Q^T for both q-groups, sharing kf
      f32x4 s[2][4] = {};
#pragma unroll
      for (int g = 0; g < 4; ++g)
#pragma unroll
        for (int c = 0; c < 2; ++c) {
          short8 kf = *(const short8*)&lK[buf][(g * 16 + li) * 64 + ((c * 4 + hi) ^ (li & 7)) * 8];
          s[0][g] = __builtin_amdgcn_mfma_f32_16x16x32_bf16(kf, qf[0][c], s[0][g], 0, 0, 0);
          s[1][g] = __builtin_amdgcn_mfma_f32_16x16x32_bf16(kf, qf[1][c], s[1][g], 0, 0, 0);
        }

#pragma unroll
      for (int grp = 0; grp < 2; ++grp) {
        const int qrow = r0 + grp * 16 + li;
        if (kt * 64 + 63 > r0 + grp * 16) {       // causal mask where tile crosses diagonal
#pragma unroll
          for (int g = 0; g < 4; ++g)
#pragma unroll
            for (int rg = 0; rg < 4; ++rg) {
              int kcol = kt * 64 + g * 16 + hi * 4 + rg;
              if (kcol > qrow) s[grp][g][rg] = -INFINITY;
            }
        }

        // tile row max: 15 in-lane fmax + 2 shuffles
        float m0 = fmaxf(fmaxf(s[grp][0][0], s[grp][0][1]), fmaxf(s[grp][0][2], s[grp][0][3]));
        float m1 = fmaxf(fmaxf(s[grp][1][0], s[grp][1][1]), fmaxf(s[grp][1][2], s[grp][1][3]));
        float m2 = fmaxf(fmaxf(s[grp][2][0], s[grp][2][1]), fmaxf(s[grp][2][2], s[grp][2][3]));
        float m3 = fmaxf(fmaxf(s[grp][3][0], s[grp][3][1]), fmaxf(s[grp][3][2], s[grp][3][3]));
        float pmax = fmaxf(fmaxf(m0, m1), fmaxf(m2, m3));
        pmax = fmaxf(pmax, __shfl_xor(pmax, 16));
        pmax = fmaxf(pmax, __shfl_xor(pmax, 32));

        // T13 defer-max (exp2 domain, THR=8)
        if (__any(pmax > mr[grp] + 8.f)) {
          float mnew = fmaxf(mr[grp], pmax);
          float sc = __builtin_amdgcn_exp2f(mr[grp] - mnew);
#pragma unroll
          for (int gd = 0; gd < 4; ++gd)
#pragma unroll
            for (int rg = 0; rg < 4; ++rg) o[grp][gd][rg] *= sc;
#pragma unroll
          for (int rg = 0; rg < 4; ++rg) o4[grp][rg] *= sc;
          mr[grp] = mnew;
        }

        // P = exp2(S - m); write to LDS as bf16 (rowsum comes from MFMA ones-trick)
#pragma unroll
        for (int g = 0; g < 4; ++g) {
          float p0 = __builtin_amdgcn_exp2f(s[grp][g][0] - mr[grp]);
          float p1 = __builtin_amdgcn_exp2f(s[grp][g][1] - mr[grp]);
          float p2 = __builtin_amdgcn_exp2f(s[grp][g][2] - mr[grp]);
          float p3 = __builtin_amdgcn_exp2f(s[grp][g][3] - mr[grp]);
          uint2 w;
          w.x = pk2bf(p0, p1);
          w.y = pk2bf(p2, p3);
          int k8s = (g * 4 + hi) ^ pswz;
          *(uint2*)&lP[wid][grp][li * 64 + k8s * 4] = w;
        }
      }

      // P as B-operand: lane reads P[q=li][c*32 + hi*8 .. +7]
      short8 pa[2][2];
#pragma unroll
      for (int grp = 0; grp < 2; ++grp)
#pragma unroll
        for (int c = 0; c < 2; ++c)
          pa[grp][c] = *(const short8*)&lP[wid][grp][li * 64 + ((c * 8 + hi * 2) ^ pswz) * 4];

      // O^T += V^T P^T, sharing vf; rowsum via ones
#pragma unroll
      for (int gd = 0; gd < 4; ++gd)
#pragma unroll
        for (int c = 0; c < 2; ++c) {
          short8 vf = *(const short8*)&lVT[buf][(gd * 16 + li) * 64 + ((c * 4 + hi) ^ (li & 7)) * 8];
          o[0][gd] = __builtin_amdgcn_mfma_f32_16x16x32_bf16(vf, pa[0][c], o[0][gd], 0, 0, 0);
          o[1][gd] = __builtin_amdgcn_mfma_f32_16x16x32_bf16(vf, pa[1][c], o[1][gd], 0, 0, 0);
        }
#pragma unroll
      for (int c = 0; c < 2; ++c) {
        o4[0] = __builtin_amdgcn_mfma_f32_16x16x32_bf16(vone, pa[0][c], o4[0], 0, 0, 0);
        o4[1] = __builtin_amdgcn_mfma_f32_16x16x32_bf16(vone, pa[1][c], o4[1], 0, 0, 0);
      }
    }

    __syncthreads();
    buf ^= 1;
  }

  // epilogue: O /= l; pack 4 bf16 (8B) per gd and store
  const int b_ = bh >> 4, h_ = bh & 15;
#pragma unroll
  for (int grp = 0; grp < 2; ++grp) {
    const float inv = 1.0f / o4[grp][0];
    const size_t rowbase = ((size_t)(b_ * NT + r0 + grp * 16 + li)) * ND + h_ * 64;
#pragma unroll
    for (int gd = 0; gd < 4; ++gd) {
      uint2 w;
      w.x = pk2bf(o[grp][gd][0] * inv, o[grp][gd][1] * inv);
      w.y = pk2bf(o[grp][gd][2] * inv, o[grp][gd][3] * inv);
      *(uint2*)&AO[rowbase + gd * 16 + hi * 4] = w;
    }
  }
}

// ---------------- RMSNorm in-place on d_out ----------------
__global__ __launch_bounds__(256) void rmsnorm_kernel(float* __restrict__ y,
                                                      const float* __restrict__ g) {
  const int row = blockIdx.x;
  const int tid = threadIdx.x;
  const int lane = tid & 63, wid = tid >> 6;
  float4 v = ((const float4*)(y + (size_t)row * ND))[tid];
  float ss = v.x * v.x + v.y * v.y + v.z * v.z + v.w * v.w;
#pragma unroll
  for (int off = 32; off; off >>= 1) ss += __shfl_down(ss, off);
  __shared__ float red[4];
  if (lane == 0) red[wid] = ss;
  __syncthreads();
  float tot = red[0] + red[1] + red[2] + red[3];
  float inv = rsqrtf(tot * (1.0f / (float)ND) + 1e-6f);
  float4 gg = ((const float4*)g)[tid];
  float4 o;
  o.x = v.x * inv * gg.x; o.y = v.y * inv * gg.y;
  o.z = v.z * inv * gg.z; o.w = v.w * inv * gg.w;
  ((float4*)(y + (size_t)row * ND))[tid] = o;
}

extern "C" void kernel_launch(void* const* d_in, const int* in_sizes, int n_in,
                              void* d_out, int out_size, void* d_ws, size_t ws_size,
                              hipStream_t stream) {
  const float* x  = (const float*)d_in[0];
  const float* wq = (const float*)d_in[1];
  const float* wk = (const float*)d_in[2];
  const float* wv = (const float*)d_in[3];
  const float* wo = (const float*)d_in[4];
  const float* ng = (const float*)d_in[5];
  float* out = (float*)d_out;

  char* ws = (char*)d_ws;
  u16* xb  = (u16*)(ws);                    // 16 MB  [M, D] bf16
  u16* wqb = (u16*)(ws + (16u << 20));      //  2 MB
  u16* wkb = (u16*)(ws + (18u << 20));
  u16* wvb = (u16*)(ws + (20u << 20));
  u16* wob = (u16*)(ws + (22u << 20));
  u16* Qb  = (u16*)(ws + (24u << 20));      // 16 MB  [B,H,T,HD]
  u16* Kb  = (u16*)(ws + (40u << 20));      // 16 MB  [B,H,T,HD]
  u16* VTb = (u16*)(ws + (56u << 20));      // 16 MB  [B,H,HD,T]  (transposed V)
  u16* AO  = (u16*)(ws + (72u << 20));      // 16 MB  [M, D]  (ends at 88 MB)

  cast_kernel<<<NM * ND / 4 / 256, 256, 0, stream>>>(x,  xb,  NM * ND / 4);
  cast_kernel<<<ND * ND / 4 / 256, 256, 0, stream>>>(wq, wqb, ND * ND / 4);
  cast_kernel<<<ND * ND / 4 / 256, 256, 0, stream>>>(wk, wkb, ND * ND / 4);
  cast_kernel<<<ND * ND / 4 / 256, 256, 0, stream>>>(wv, wvb, ND * ND / 4);
  cast_kernel<<<ND * ND / 4 / 256, 256, 0, stream>>>(wo, wob, ND * ND / 4);

  gemm_qkv<<<dim3(NM / 128, ND / 128, 3), 256, 0, stream>>>(xb, wqb, wkb, wvb, Qb, Kb, VTb);
  attn_kernel<<<dim3(16, NB * NH), 256, 0, stream>>>(Qb, Kb, VTb, AO);
  gemm_wo<<<dim3(NM / 128, ND / 128), 256, 0, stream>>>(AO, wob, x, out);
  rmsnorm_kernel<<<NM, 256, 0, stream>>>(out, ng);
}

// Round 6
// 226.995 us; speedup vs baseline: 1.1442x; 1.1442x over previous
//
#include <hip/hip_runtime.h>
#include <hip/hip_bf16.h>

// Problem constants (B=4, T=2048, D=1024, H=16, HD=64)
constexpr int NB  = 4;
constexpr int NT  = 2048;
constexpr int ND  = 1024;
constexpr int NH  = 16;
constexpr int NHD = 64;
constexpr int NM  = NB * NT;   // 8192 tokens

typedef unsigned short u16;
typedef __attribute__((ext_vector_type(8))) short  short8;  // 8 bf16 (4 VGPRs)
typedef __attribute__((ext_vector_type(4))) float  f32x4;   // MFMA acc

__device__ __forceinline__ u16 f2bf(float f) {
  unsigned u = __builtin_bit_cast(unsigned, f);
  u += 0x7FFFu + ((u >> 16) & 1u);   // round-to-nearest-even
  return (u16)(u >> 16);
}

// pack two f32 -> 2x bf16 in one dword (compiler emits v_cvt_pk_bf16_f32)
__device__ __forceinline__ unsigned pk2bf(float lo, float hi_) {
  float2 t; t.x = lo; t.y = hi_;
  __hip_bfloat162 h2 = __float22bfloat162_rn(t);
  unsigned u;
  __builtin_memcpy(&u, &h2, 4);
  return u;
}

// async global->LDS, 16B per lane. dst must be wave-uniform; lane i lands at dst + i*16B.
__device__ __forceinline__ void gll16(const u16* src, u16* dst) {
  __builtin_amdgcn_global_load_lds(
      (const __attribute__((address_space(1))) void*)src,
      (__attribute__((address_space(3))) void*)dst, 16, 0, 0);
}

// ---------------- cast f32 -> bf16, vectorized x4 ----------------
__global__ __launch_bounds__(256) void cast_kernel(const float* __restrict__ in,
                                                   u16* __restrict__ out, int n4) {
  int i = blockIdx.x * 256 + threadIdx.x;
  if (i >= n4) return;
  float4 v = ((const float4*)in)[i];
  ushort4 o;
  o.x = f2bf(v.x); o.y = f2bf(v.y); o.z = f2bf(v.z); o.w = f2bf(v.w);
  ((ushort4*)out)[i] = o;
}

// ---------------- QKV GEMM: y = x @ W^T ----------------
// Q,K scattered to [B,H,T,HD] (swapped-orientation MFMA: rg = 4 consecutive d -> uint2 store);
// V scattered TRANSPOSED to [B,H,HD,T] (normal orientation: rg = 4 consecutive t -> uint2 store).
__global__ __launch_bounds__(256) void gemm_qkv(
    const u16* __restrict__ xb,
    const u16* __restrict__ wqb, const u16* __restrict__ wkb, const u16* __restrict__ wvb,
    u16* __restrict__ Qb, u16* __restrict__ Kb, u16* __restrict__ VTb) {
  const int z = blockIdx.z;
  const u16* wsel = (z == 0) ? wqb : (z == 1) ? wkb : wvb;
  u16* osel      = (z == 0) ? Qb  : (z == 1) ? Kb  : VTb;
  // attention scale + log2(e) folded into Q (softmax done in exp2 domain)
  const float scl = (z == 0) ? 0.125f * 1.44269504f : 1.0f;

  const int row0 = blockIdx.x * 128;
  const int col0 = blockIdx.y * 128;
  const int tid  = threadIdx.x;
  const int lane = tid & 63, wid = tid >> 6;
  const int wm = wid >> 1, wn = wid & 1;
  const int li = lane & 15, hi = lane >> 4;

  __shared__ __align__(16) u16 lA[128 * 32];
  __shared__ __align__(16) u16 lB[128 * 32];

  f32x4 acc[4][4] = {};
  const int rl = lane >> 2;   // 0..15 (row within 16-row slab)
  const int c8 = lane & 3;    // 8-elem chunk within 32-elem row

  for (int k0 = 0; k0 < ND; k0 += 32) {
#pragma unroll
    for (int h = 0; h < 2; ++h) {
      int r = wid * 32 + h * 16 + rl;
      gll16(&xb  [(size_t)(row0 + r) * ND + k0 + c8 * 8], &lA[(wid * 32 + h * 16) * 32]);
      gll16(&wsel[(size_t)(col0 + r) * ND + k0 + c8 * 8], &lB[(wid * 32 + h * 16) * 32]);
    }
    __syncthreads();
    short8 a[4], b[4];
#pragma unroll
    for (int m = 0; m < 4; ++m)
      a[m] = *(const short8*)&lA[(wm * 64 + m * 16 + li) * 32 + hi * 8];
#pragma unroll
    for (int n = 0; n < 4; ++n)
      b[n] = *(const short8*)&lB[(wn * 64 + n * 16 + li) * 32 + hi * 8];
    if (z == 2) {
#pragma unroll
      for (int m = 0; m < 4; ++m)
#pragma unroll
        for (int n = 0; n < 4; ++n)
          acc[m][n] = __builtin_amdgcn_mfma_f32_16x16x32_bf16(a[m], b[n], acc[m][n], 0, 0, 0);
    } else {  // swapped: acc = C^T fragment (row=feature, col=token)
#pragma unroll
      for (int m = 0; m < 4; ++m)
#pragma unroll
        for (int n = 0; n < 4; ++n)
          acc[m][n] = __builtin_amdgcn_mfma_f32_16x16x32_bf16(b[n], a[m], acc[m][n], 0, 0, 0);
    }
    __syncthreads();
  }

#pragma unroll
  for (int m = 0; m < 4; ++m)
#pragma unroll
    for (int n = 0; n < 4; ++n) {
      if (z == 2) {
        // normal: row=token(hi*4+rg), col=feature(li). Pack 4 consecutive t.
        int token0 = row0 + wm * 64 + m * 16 + hi * 4;
        int col    = col0 + wn * 64 + n * 16 + li;
        int b_ = token0 >> 11, t0 = token0 & (NT - 1);
        int h_ = col >> 6,     d_ = col & (NHD - 1);
        uint2 w;
        w.x = pk2bf(acc[m][n][0], acc[m][n][1]);
        w.y = pk2bf(acc[m][n][2], acc[m][n][3]);
        *(uint2*)&osel[(((size_t)(b_ * NH + h_)) * NHD + d_) * NT + t0] = w;
      } else {
        // swapped: row=feature(hi*4+rg), col=token(li). Pack 4 consecutive d.
        int token = row0 + wm * 64 + m * 16 + li;
        int feat0 = col0 + wn * 64 + n * 16 + hi * 4;
        int b_ = token >> 11, t_ = token & (NT - 1);
        int h_ = feat0 >> 6,  d0 = feat0 & (NHD - 1);
        uint2 w;
        w.x = pk2bf(acc[m][n][0] * scl, acc[m][n][1] * scl);
        w.y = pk2bf(acc[m][n][2] * scl, acc[m][n][3] * scl);
        *(uint2*)&osel[(((size_t)(b_ * NH + h_)) * NT + t_) * NHD + d0] = w;
      }
    }
}

// ---------------- WO GEMM + residual: out = x + AO @ WO^T (f32 out) ----------------
// Swapped orientation: rg = 4 consecutive features -> float4 load/store.
__global__ __launch_bounds__(256) void gemm_wo(
    const u16* __restrict__ ao, const u16* __restrict__ wob,
    const float* __restrict__ x, float* __restrict__ y) {
  const int row0 = blockIdx.x * 128;
  const int col0 = blockIdx.y * 128;
  const int tid  = threadIdx.x;
  const int lane = tid & 63, wid = tid >> 6;
  const int wm = wid >> 1, wn = wid & 1;
  const int li = lane & 15, hi = lane >> 4;

  __shared__ __align__(16) u16 lA[128 * 32];
  __shared__ __align__(16) u16 lB[128 * 32];

  f32x4 acc[4][4] = {};
  const int rl = lane >> 2;
  const int c8 = lane & 3;

  for (int k0 = 0; k0 < ND; k0 += 32) {
#pragma unroll
    for (int h = 0; h < 2; ++h) {
      int r = wid * 32 + h * 16 + rl;
      gll16(&ao [(size_t)(row0 + r) * ND + k0 + c8 * 8], &lA[(wid * 32 + h * 16) * 32]);
      gll16(&wob[(size_t)(col0 + r) * ND + k0 + c8 * 8], &lB[(wid * 32 + h * 16) * 32]);
    }
    __syncthreads();
    short8 a[4], b[4];
#pragma unroll
    for (int m = 0; m < 4; ++m)
      a[m] = *(const short8*)&lA[(wm * 64 + m * 16 + li) * 32 + hi * 8];
#pragma unroll
    for (int n = 0; n < 4; ++n)
      b[n] = *(const short8*)&lB[(wn * 64 + n * 16 + li) * 32 + hi * 8];
#pragma unroll
    for (int m = 0; m < 4; ++m)
#pragma unroll
      for (int n = 0; n < 4; ++n)
        acc[m][n] = __builtin_amdgcn_mfma_f32_16x16x32_bf16(b[n], a[m], acc[m][n], 0, 0, 0);
    __syncthreads();
  }

#pragma unroll
  for (int m = 0; m < 4; ++m)
#pragma unroll
    for (int n = 0; n < 4; ++n) {
      int token = row0 + wm * 64 + m * 16 + li;
      int feat0 = col0 + wn * 64 + n * 16 + hi * 4;
      size_t idx = (size_t)token * ND + feat0;
      float4 xv = *(const float4*)&x[idx];
      float4 o;
      o.x = acc[m][n][0] + xv.x; o.y = acc[m][n][1] + xv.y;
      o.z = acc[m][n][2] + xv.z; o.w = acc[m][n][3] + xv.w;
      *(float4*)&y[idx] = o;
    }
}

// ---------------- causal flash attention ----------------
// grid 2048 (32 q-tiles x 64 bh), XCD-swizzled + heavy-first. 4 waves; wave owns 16 q-rows.
// T14 reg-staged pipeline: issue global loads (tile kt+1) at top of iter, ds_write after
// compute -> HBM latency hides under compute, vmcnt=0 at the barrier (no drain stall).
// S = mfma(K, Q); O = mfma(V^T, P); rowsum via mfma(ones, P) accumulator.
__global__ __launch_bounds__(256) void attn_kernel(
    const u16* __restrict__ Q, const u16* __restrict__ K, const u16* __restrict__ VT,
    u16* __restrict__ AO) {
  // T1: XCD-aware swizzle (2048 % 8 == 0 -> bijective)
  const int nb  = gridDim.x * gridDim.y;           // 2048
  const int b0  = blockIdx.y * gridDim.x + blockIdx.x;
  const int L   = (b0 & 7) * (nb >> 3) + (b0 >> 3);
  const int qb  = 31 - (L & 31);     // heavy-first: big qb dispatched early
  const int bh  = L >> 5;            // 0..63

  const int tid = threadIdx.x;
  const int lane = tid & 63, wid = tid >> 6;
  const int li = lane & 15, hi = lane >> 4;
  const int r0 = qb * 64 + wid * 16;         // wave's q rows
  const int qrow = r0 + li;                  // this lane's q row
  const size_t bK = (size_t)bh * NT * NHD;   // K  [bh][t][d]
  const size_t bV = (size_t)bh * NHD * NT;   // VT [bh][d][t]

  __shared__ __align__(16) u16 lK [2][64 * 64];
  __shared__ __align__(16) u16 lVT[2][64 * 64];
  __shared__ __align__(16) u16 lP [4][16 * 64];

  // ---- reg-staging geometry: 512 chunks of 8 u16 per tile; thread owns ch0=tid, ch1=tid+256
  const int ch0 = tid, ch1 = tid + 256;
  // LDS dest (XOR chunk swizzle): row=ch>>3, slot=(ch&7)^(row&7)
  const int d0 = (ch0 >> 3) * 64 + (((ch0 & 7) ^ ((ch0 >> 3) & 7)) << 3);
  const int d1 = (ch1 >> 3) * 64 + (((ch1 & 7) ^ ((ch1 >> 3) & 7)) << 3);
  // K global: chunk ch of tile kt at bK + kt*4096 + ch*8 (contiguous)
  // VT global: row=ch>>3 (d), col8=ch&7 -> bV + (ch>>3)*NT + kt*64 + (ch&7)*8
  const int vOff0 = (ch0 >> 3) * NT + (ch0 & 7) * 8;
  const int vOff1 = (ch1 >> 3) * NT + (ch1 & 7) * 8;

  uint4 gK0, gK1, gV0, gV1;
  auto issue = [&](int kt) {
    const u16* kp = K + bK + (size_t)kt * 4096;
    const u16* vp = VT + bV + kt * 64;
    gK0 = *(const uint4*)&kp[ch0 * 8];
    gK1 = *(const uint4*)&kp[ch1 * 8];
    gV0 = *(const uint4*)&vp[vOff0];
    gV1 = *(const uint4*)&vp[vOff1];
  };
  auto commit = [&](int buf) {
    *(uint4*)&lK [buf][d0] = gK0;
    *(uint4*)&lK [buf][d1] = gK1;
    *(uint4*)&lVT[buf][d0] = gV0;
    *(uint4*)&lVT[buf][d1] = gV1;
  };

  // Q fragments (B-operand): lane holds Q[qrow][c*32 + hi*8 + e]
  short8 qf[2];
#pragma unroll
  for (int c = 0; c < 2; ++c)
    qf[c] = *(const short8*)&Q[bK + (size_t)qrow * NHD + c * 32 + hi * 8];

  short8 vone;
#pragma unroll
  for (int e = 0; e < 8; ++e) vone[e] = (short)0x3F80;   // bf16 1.0

  f32x4 o[4] = {};
  f32x4 o4 = {};          // rowsum accumulator (all 4 regs equal)
  float mr = -INFINITY;   // running row max (exp2 domain), per-lane (q=li)

  issue(0);
  commit(0);
  __syncthreads();
  int buf = 0;

  const int pswz = (li & 7) << 1;   // P-LDS XOR swizzle (8B chunks, bit0 preserved)

  for (int kt = 0; kt <= qb; ++kt) {
    if (kt < qb) issue(kt + 1);    // loads in flight under the compute below

    // S^T = K Q^T : s[g][rg] = S[q=li][k = g*16 + hi*4 + rg]
    f32x4 s[4] = {};
    __builtin_amdgcn_s_setprio(1);
#pragma unroll
    for (int g = 0; g < 4; ++g)
#pragma unroll
      for (int c = 0; c < 2; ++c) {
        short8 kf = *(const short8*)&lK[buf][(g * 16 + li) * 64 + ((c * 4 + hi) ^ (li & 7)) * 8];
        s[g] = __builtin_amdgcn_mfma_f32_16x16x32_bf16(kf, qf[c], s[g], 0, 0, 0);
      }
    __builtin_amdgcn_s_setprio(0);

    if (kt == qb) {                          // causal mask on diagonal tile
#pragma unroll
      for (int g = 0; g < 4; ++g)
#pragma unroll
        for (int rg = 0; rg < 4; ++rg) {
          int kcol = kt * 64 + g * 16 + hi * 4 + rg;
          if (kcol > qrow) s[g][rg] = -INFINITY;
        }
    }

    // tile row max: 15 in-lane fmax + 2 shuffles
    float mg0 = fmaxf(fmaxf(s[0][0], s[0][1]), fmaxf(s[0][2], s[0][3]));
    float mg1 = fmaxf(fmaxf(s[1][0], s[1][1]), fmaxf(s[1][2], s[1][3]));
    float mg2 = fmaxf(fmaxf(s[2][0], s[2][1]), fmaxf(s[2][2], s[2][3]));
    float mg3 = fmaxf(fmaxf(s[3][0], s[3][1]), fmaxf(s[3][2], s[3][3]));
    float pmax = fmaxf(fmaxf(mg0, mg1), fmaxf(mg2, mg3));
    pmax = fmaxf(pmax, __shfl_xor(pmax, 16));
    pmax = fmaxf(pmax, __shfl_xor(pmax, 32));

    // T13 defer-max: only rescale when the tile max exceeds m by > 8 (exp2 domain)
    if (__any(pmax > mr + 8.f)) {
      float mnew = fmaxf(mr, pmax);
      float sc = __builtin_amdgcn_exp2f(mr - mnew);
#pragma unroll
      for (int gd = 0; gd < 4; ++gd)
#pragma unroll
        for (int rg = 0; rg < 4; ++rg) o[gd][rg] *= sc;
#pragma unroll
      for (int rg = 0; rg < 4; ++rg) o4[rg] *= sc;
      mr = mnew;
    }

    // P = exp2(S - m) -> LDS as bf16 (rowsum comes from the MFMA ones-trick)
#pragma unroll
    for (int g = 0; g < 4; ++g) {
      float p0 = __builtin_amdgcn_exp2f(s[g][0] - mr);
      float p1 = __builtin_amdgcn_exp2f(s[g][1] - mr);
      float p2 = __builtin_amdgcn_exp2f(s[g][2] - mr);
      float p3 = __builtin_amdgcn_exp2f(s[g][3] - mr);
      uint2 w;
      w.x = pk2bf(p0, p1);
      w.y = pk2bf(p2, p3);
      int k8s = (g * 4 + hi) ^ pswz;
      *(uint2*)&lP[wid][li * 64 + k8s * 4] = w;
    }

    // P as B-operand: lane reads P[q=li][c*32 + hi*8 .. +7]
    short8 pa[2];
#pragma unroll
    for (int c = 0; c < 2; ++c)
      pa[c] = *(const short8*)&lP[wid][li * 64 + ((c * 8 + hi * 2) ^ pswz) * 4];

    // O^T += V^T P^T ; rowsum via ones
    __builtin_amdgcn_s_setprio(1);
#pragma unroll
    for (int gd = 0; gd < 4; ++gd)
#pragma unroll
      for (int c = 0; c < 2; ++c) {
        short8 vf = *(const short8*)&lVT[buf][(gd * 16 + li) * 64 + ((c * 4 + hi) ^ (li & 7)) * 8];
        o[gd] = __builtin_amdgcn_mfma_f32_16x16x32_bf16(vf, pa[c], o[gd], 0, 0, 0);
      }
#pragma unroll
    for (int c = 0; c < 2; ++c)
      o4 = __builtin_amdgcn_mfma_f32_16x16x32_bf16(vone, pa[c], o4, 0, 0, 0);
    __builtin_amdgcn_s_setprio(0);

    if (kt < qb) commit(buf ^ 1);   // vmcnt consumed here (hidden under compute above)
    __syncthreads();                // vmcnt already 0 -> no drain stall
    buf ^= 1;
  }

  // epilogue: O /= l; pack 4 bf16 (8B) per gd and store
  const int b_ = bh >> 4, h_ = bh & 15;
  const float inv = 1.0f / o4[0];
  const size_t rowbase = ((size_t)(b_ * NT + qrow)) * ND + h_ * 64;
#pragma unroll
  for (int gd = 0; gd < 4; ++gd) {
    uint2 w;
    w.x = pk2bf(o[gd][0] * inv, o[gd][1] * inv);
    w.y = pk2bf(o[gd][2] * inv, o[gd][3] * inv);
    *(uint2*)&AO[rowbase + gd * 16 + hi * 4] = w;
  }
}

// ---------------- RMSNorm in-place on d_out ----------------
__global__ __launch_bounds__(256) void rmsnorm_kernel(float* __restrict__ y,
                                                      const float* __restrict__ g) {
  const int row = blockIdx.x;
  const int tid = threadIdx.x;
  const int lane = tid & 63, wid = tid >> 6;
  float4 v = ((const float4*)(y + (size_t)row * ND))[tid];
  float ss = v.x * v.x + v.y * v.y + v.z * v.z + v.w * v.w;
#pragma unroll
  for (int off = 32; off; off >>= 1) ss += __shfl_down(ss, off);
  __shared__ float red[4];
  if (lane == 0) red[wid] = ss;
  __syncthreads();
  float tot = red[0] + red[1] + red[2] + red[3];
  float inv = rsqrtf(tot * (1.0f / (float)ND) + 1e-6f);
  float4 gg = ((const float4*)g)[tid];
  float4 o;
  o.x = v.x * inv * gg.x; o.y = v.y * inv * gg.y;
  o.z = v.z * inv * gg.z; o.w = v.w * inv * gg.w;
  ((float4*)(y + (size_t)row * ND))[tid] = o;
}

extern "C" void kernel_launch(void* const* d_in, const int* in_sizes, int n_in,
                              void* d_out, int out_size, void* d_ws, size_t ws_size,
                              hipStream_t stream) {
  const float* x  = (const float*)d_in[0];
  const float* wq = (const float*)d_in[1];
  const float* wk = (const float*)d_in[2];
  const float* wv = (const float*)d_in[3];
  const float* wo = (const float*)d_in[4];
  const float* ng = (const float*)d_in[5];
  float* out = (float*)d_out;

  char* ws = (char*)d_ws;
  u16* xb  = (u16*)(ws);                    // 16 MB  [M, D] bf16
  u16* wqb = (u16*)(ws + (16u << 20));      //  2 MB
  u16* wkb = (u16*)(ws + (18u << 20));
  u16* wvb = (u16*)(ws + (20u << 20));
  u16* wob = (u16*)(ws + (22u << 20));
  u16* Qb  = (u16*)(ws + (24u << 20));      // 16 MB  [B,H,T,HD]
  u16* Kb  = (u16*)(ws + (40u << 20));      // 16 MB  [B,H,T,HD]
  u16* VTb = (u16*)(ws + (56u << 20));      // 16 MB  [B,H,HD,T]  (transposed V)
  u16* AO  = (u16*)(ws + (72u << 20));      // 16 MB  [M, D]  (ends at 88 MB)

  cast_kernel<<<NM * ND / 4 / 256, 256, 0, stream>>>(x,  xb,  NM * ND / 4);
  cast_kernel<<<ND * ND / 4 / 256, 256, 0, stream>>>(wq, wqb, ND * ND / 4);
  cast_kernel<<<ND * ND / 4 / 256, 256, 0, stream>>>(wk, wkb, ND * ND / 4);
  cast_kernel<<<ND * ND / 4 / 256, 256, 0, stream>>>(wv, wvb, ND * ND / 4);
  cast_kernel<<<ND * ND / 4 / 256, 256, 0, stream>>>(wo, wob, ND * ND / 4);

  gemm_qkv<<<dim3(NM / 128, ND / 128, 3), 256, 0, stream>>>(xb, wqb, wkb, wvb, Qb, Kb, VTb);
  attn_kernel<<<dim3(NT / 64, NB * NH), 256, 0, stream>>>(Qb, Kb, VTb, AO);
  gemm_wo<<<dim3(NM / 128, ND / 128), 256, 0, stream>>>(AO, wob, x, out);
  rmsnorm_kernel<<<NM, 256, 0, stream>>>(out, ng);
}

// Round 7
// 219.284 us; speedup vs baseline: 1.1845x; 1.0352x over previous
//
#include <hip/hip_runtime.h>
#include <hip/hip_bf16.h>

// Problem constants (B=4, T=2048, D=1024, H=16, HD=64)
constexpr int NB  = 4;
constexpr int NT  = 2048;
constexpr int ND  = 1024;
constexpr int NH  = 16;
constexpr int NHD = 64;
constexpr int NM  = NB * NT;   // 8192 tokens

typedef unsigned short u16;
typedef __attribute__((ext_vector_type(8))) short  short8;  // 8 bf16 (4 VGPRs)
typedef __attribute__((ext_vector_type(4))) float  f32x4;   // MFMA acc

__device__ __forceinline__ u16 f2bf(float f) {
  unsigned u = __builtin_bit_cast(unsigned, f);
  u += 0x7FFFu + ((u >> 16) & 1u);   // round-to-nearest-even
  return (u16)(u >> 16);
}

// pack two f32 -> 2x bf16 in one dword (compiler emits v_cvt_pk_bf16_f32)
__device__ __forceinline__ unsigned pk2bf(float lo, float hi_) {
  float2 t; t.x = lo; t.y = hi_;
  __hip_bfloat162 h2 = __float22bfloat162_rn(t);
  unsigned u;
  __builtin_memcpy(&u, &h2, 4);
  return u;
}

// async global->LDS, 16B per lane. dst must be wave-uniform; lane i lands at dst + i*16B.
__device__ __forceinline__ void gll16(const u16* src, u16* dst) {
  __builtin_amdgcn_global_load_lds(
      (const __attribute__((address_space(1))) void*)src,
      (__attribute__((address_space(3))) void*)dst, 16, 0, 0);
}

// ---------------- cast f32 -> bf16, vectorized x4 ----------------
__global__ __launch_bounds__(256) void cast_kernel(const float* __restrict__ in,
                                                   u16* __restrict__ out, int n4) {
  int i = blockIdx.x * 256 + threadIdx.x;
  if (i >= n4) return;
  float4 v = ((const float4*)in)[i];
  ushort4 o;
  o.x = f2bf(v.x); o.y = f2bf(v.y); o.z = f2bf(v.z); o.w = f2bf(v.w);
  ((ushort4*)out)[i] = o;
}

// cast all 4 weight matrices in one launch (1024 blocks each)
__global__ __launch_bounds__(256) void cast4_kernel(
    const float* __restrict__ w0, const float* __restrict__ w1,
    const float* __restrict__ w2, const float* __restrict__ w3,
    u16* __restrict__ o0, u16* __restrict__ o1,
    u16* __restrict__ o2, u16* __restrict__ o3) {
  const int z = blockIdx.x >> 10;
  const float* in = (z == 0) ? w0 : (z == 1) ? w1 : (z == 2) ? w2 : w3;
  u16* out       = (z == 0) ? o0 : (z == 1) ? o1 : (z == 2) ? o2 : o3;
  int i = (blockIdx.x & 1023) * 256 + threadIdx.x;
  float4 v = ((const float4*)in)[i];
  ushort4 o;
  o.x = f2bf(v.x); o.y = f2bf(v.y); o.z = f2bf(v.z); o.w = f2bf(v.w);
  ((ushort4*)out)[i] = o;
}

// ---------------- QKV GEMM: y = x @ W^T ----------------
// BK=64 tiles ([128][64] u16 = 128B rows), XOR chunk-swizzle staging (conflict-free,
// proven in attn r2). Q,K scattered to [B,H,T,HD] (swapped MFMA -> uint2 of 4 d);
// V scattered TRANSPOSED to [B,H,HD,T] (normal -> uint2 of 4 t).
__global__ __launch_bounds__(256) void gemm_qkv(
    const u16* __restrict__ xb,
    const u16* __restrict__ wqb, const u16* __restrict__ wkb, const u16* __restrict__ wvb,
    u16* __restrict__ Qb, u16* __restrict__ Kb, u16* __restrict__ VTb) {
  // T1: XCD-chunked swizzle over flat grid (1536 % 8 == 0 -> bijective)
  const int nwg  = 64 * 8 * 3;
  const int flat = (blockIdx.z * 8 + blockIdx.y) * 64 + blockIdx.x;
  const int L    = (flat & 7) * (nwg >> 3) + (flat >> 3);
  const int z    = L / 512;
  const int rem  = L & 511;
  const int col0 = (rem >> 6) << 7;
  const int row0 = (rem & 63) << 7;

  const u16* wsel = (z == 0) ? wqb : (z == 1) ? wkb : wvb;
  u16* osel      = (z == 0) ? Qb  : (z == 1) ? Kb  : VTb;
  // attention scale + log2(e) folded into Q (softmax done in exp2 domain)
  const float scl = (z == 0) ? 0.125f * 1.44269504f : 1.0f;

  const int tid  = threadIdx.x;
  const int lane = tid & 63, wid = tid >> 6;
  const int wm = wid >> 1, wn = wid & 1;
  const int li = lane & 15, hi = lane >> 4;
  const int rl8 = lane >> 3, sl = lane & 7;

  __shared__ __align__(16) u16 lA[128 * 64];
  __shared__ __align__(16) u16 lB[128 * 64];

  f32x4 acc[4][4] = {};

  for (int k0 = 0; k0 < ND; k0 += 64) {
#pragma unroll
    for (int h = 0; h < 4; ++h) {
      int r  = wid * 32 + h * 8 + rl8;
      int cs = ((sl ^ (r & 7)) << 3);
      gll16(&xb  [(size_t)(row0 + r) * ND + k0 + cs], &lA[(wid * 32 + h * 8) * 64]);
      gll16(&wsel[(size_t)(col0 + r) * ND + k0 + cs], &lB[(wid * 32 + h * 8) * 64]);
    }
    __syncthreads();
    short8 a[4][2], b[4][2];
#pragma unroll
    for (int m = 0; m < 4; ++m)
#pragma unroll
      for (int c = 0; c < 2; ++c)
        a[m][c] = *(const short8*)&lA[(wm * 64 + m * 16 + li) * 64 + (((c * 4 + hi) ^ (li & 7)) << 3)];
#pragma unroll
    for (int n = 0; n < 4; ++n)
#pragma unroll
      for (int c = 0; c < 2; ++c)
        b[n][c] = *(const short8*)&lB[(wn * 64 + n * 16 + li) * 64 + (((c * 4 + hi) ^ (li & 7)) << 3)];
    if (z == 2) {
#pragma unroll
      for (int m = 0; m < 4; ++m)
#pragma unroll
        for (int n = 0; n < 4; ++n)
#pragma unroll
          for (int c = 0; c < 2; ++c)
            acc[m][n] = __builtin_amdgcn_mfma_f32_16x16x32_bf16(a[m][c], b[n][c], acc[m][n], 0, 0, 0);
    } else {  // swapped: acc = C^T fragment (row=feature, col=token)
#pragma unroll
      for (int m = 0; m < 4; ++m)
#pragma unroll
        for (int n = 0; n < 4; ++n)
#pragma unroll
          for (int c = 0; c < 2; ++c)
            acc[m][n] = __builtin_amdgcn_mfma_f32_16x16x32_bf16(b[n][c], a[m][c], acc[m][n], 0, 0, 0);
    }
    __syncthreads();
  }

#pragma unroll
  for (int m = 0; m < 4; ++m)
#pragma unroll
    for (int n = 0; n < 4; ++n) {
      if (z == 2) {
        // normal: row=token(hi*4+rg), col=feature(li). Pack 4 consecutive t.
        int token0 = row0 + wm * 64 + m * 16 + hi * 4;
        int col    = col0 + wn * 64 + n * 16 + li;
        int b_ = token0 >> 11, t0 = token0 & (NT - 1);
        int h_ = col >> 6,     d_ = col & (NHD - 1);
        uint2 w;
        w.x = pk2bf(acc[m][n][0], acc[m][n][1]);
        w.y = pk2bf(acc[m][n][2], acc[m][n][3]);
        *(uint2*)&osel[(((size_t)(b_ * NH + h_)) * NHD + d_) * NT + t0] = w;
      } else {
        // swapped: row=feature(hi*4+rg), col=token(li). Pack 4 consecutive d.
        int token = row0 + wm * 64 + m * 16 + li;
        int feat0 = col0 + wn * 64 + n * 16 + hi * 4;
        int b_ = token >> 11, t_ = token & (NT - 1);
        int h_ = feat0 >> 6,  d0 = feat0 & (NHD - 1);
        uint2 w;
        w.x = pk2bf(acc[m][n][0] * scl, acc[m][n][1] * scl);
        w.y = pk2bf(acc[m][n][2] * scl, acc[m][n][3] * scl);
        *(uint2*)&osel[(((size_t)(b_ * NH + h_)) * NT + t_) * NHD + d0] = w;
      }
    }
}

// ---------------- WO GEMM + residual: out = x + AO @ WO^T (f32 out) ----------------
// BK=64 + XOR chunk-swizzle; swapped orientation -> float4 load/store epilogue.
__global__ __launch_bounds__(256) void gemm_wo(
    const u16* __restrict__ ao, const u16* __restrict__ wob,
    const float* __restrict__ x, float* __restrict__ y) {
  const int nwg  = 64 * 8;
  const int flat = blockIdx.y * 64 + blockIdx.x;
  const int L    = (flat & 7) * (nwg >> 3) + (flat >> 3);
  const int col0 = (L >> 6) << 7;
  const int row0 = (L & 63) << 7;

  const int tid  = threadIdx.x;
  const int lane = tid & 63, wid = tid >> 6;
  const int wm = wid >> 1, wn = wid & 1;
  const int li = lane & 15, hi = lane >> 4;
  const int rl8 = lane >> 3, sl = lane & 7;

  __shared__ __align__(16) u16 lA[128 * 64];
  __shared__ __align__(16) u16 lB[128 * 64];

  f32x4 acc[4][4] = {};

  for (int k0 = 0; k0 < ND; k0 += 64) {
#pragma unroll
    for (int h = 0; h < 4; ++h) {
      int r  = wid * 32 + h * 8 + rl8;
      int cs = ((sl ^ (r & 7)) << 3);
      gll16(&ao [(size_t)(row0 + r) * ND + k0 + cs], &lA[(wid * 32 + h * 8) * 64]);
      gll16(&wob[(size_t)(col0 + r) * ND + k0 + cs], &lB[(wid * 32 + h * 8) * 64]);
    }
    __syncthreads();
    short8 a[4][2], b[4][2];
#pragma unroll
    for (int m = 0; m < 4; ++m)
#pragma unroll
      for (int c = 0; c < 2; ++c)
        a[m][c] = *(const short8*)&lA[(wm * 64 + m * 16 + li) * 64 + (((c * 4 + hi) ^ (li & 7)) << 3)];
#pragma unroll
    for (int n = 0; n < 4; ++n)
#pragma unroll
      for (int c = 0; c < 2; ++c)
        b[n][c] = *(const short8*)&lB[(wn * 64 + n * 16 + li) * 64 + (((c * 4 + hi) ^ (li & 7)) << 3)];
#pragma unroll
    for (int m = 0; m < 4; ++m)
#pragma unroll
      for (int n = 0; n < 4; ++n)
#pragma unroll
        for (int c = 0; c < 2; ++c)
          acc[m][n] = __builtin_amdgcn_mfma_f32_16x16x32_bf16(b[n][c], a[m][c], acc[m][n], 0, 0, 0);
    __syncthreads();
  }

#pragma unroll
  for (int m = 0; m < 4; ++m)
#pragma unroll
    for (int n = 0; n < 4; ++n) {
      int token = row0 + wm * 64 + m * 16 + li;
      int feat0 = col0 + wn * 64 + n * 16 + hi * 4;
      size_t idx = (size_t)token * ND + feat0;
      float4 xv = *(const float4*)&x[idx];
      float4 o;
      o.x = acc[m][n][0] + xv.x; o.y = acc[m][n][1] + xv.y;
      o.z = acc[m][n][2] + xv.z; o.w = acc[m][n][3] + xv.w;
      *(float4*)&y[idx] = o;
    }
}

// ---------------- causal flash attention (unchanged from r6) ----------------
__global__ __launch_bounds__(256) void attn_kernel(
    const u16* __restrict__ Q, const u16* __restrict__ K, const u16* __restrict__ VT,
    u16* __restrict__ AO) {
  // T1: XCD-aware swizzle (2048 % 8 == 0 -> bijective)
  const int nb  = gridDim.x * gridDim.y;           // 2048
  const int b0  = blockIdx.y * gridDim.x + blockIdx.x;
  const int L   = (b0 & 7) * (nb >> 3) + (b0 >> 3);
  const int qb  = 31 - (L & 31);     // heavy-first: big qb dispatched early
  const int bh  = L >> 5;            // 0..63

  const int tid = threadIdx.x;
  const int lane = tid & 63, wid = tid >> 6;
  const int li = lane & 15, hi = lane >> 4;
  const int r0 = qb * 64 + wid * 16;         // wave's q rows
  const int qrow = r0 + li;                  // this lane's q row
  const size_t bK = (size_t)bh * NT * NHD;   // K  [bh][t][d]
  const size_t bV = (size_t)bh * NHD * NT;   // VT [bh][d][t]

  __shared__ __align__(16) u16 lK [2][64 * 64];
  __shared__ __align__(16) u16 lVT[2][64 * 64];
  __shared__ __align__(16) u16 lP [4][16 * 64];

  // ---- reg-staging geometry: 512 chunks of 8 u16 per tile; thread owns ch0=tid, ch1=tid+256
  const int ch0 = tid, ch1 = tid + 256;
  // LDS dest (XOR chunk swizzle): row=ch>>3, slot=(ch&7)^(row&7)
  const int d0 = (ch0 >> 3) * 64 + (((ch0 & 7) ^ ((ch0 >> 3) & 7)) << 3);
  const int d1 = (ch1 >> 3) * 64 + (((ch1 & 7) ^ ((ch1 >> 3) & 7)) << 3);
  // K global: chunk ch of tile kt at bK + kt*4096 + ch*8 (contiguous)
  // VT global: row=ch>>3 (d), col8=ch&7 -> bV + (ch>>3)*NT + kt*64 + (ch&7)*8
  const int vOff0 = (ch0 >> 3) * NT + (ch0 & 7) * 8;
  const int vOff1 = (ch1 >> 3) * NT + (ch1 & 7) * 8;

  uint4 gK0, gK1, gV0, gV1;
  auto issue = [&](int kt) {
    const u16* kp = K + bK + (size_t)kt * 4096;
    const u16* vp = VT + bV + kt * 64;
    gK0 = *(const uint4*)&kp[ch0 * 8];
    gK1 = *(const uint4*)&kp[ch1 * 8];
    gV0 = *(const uint4*)&vp[vOff0];
    gV1 = *(const uint4*)&vp[vOff1];
  };
  auto commit = [&](int buf) {
    *(uint4*)&lK [buf][d0] = gK0;
    *(uint4*)&lK [buf][d1] = gK1;
    *(uint4*)&lVT[buf][d0] = gV0;
    *(uint4*)&lVT[buf][d1] = gV1;
  };

  // Q fragments (B-operand): lane holds Q[qrow][c*32 + hi*8 + e]
  short8 qf[2];
#pragma unroll
  for (int c = 0; c < 2; ++c)
    qf[c] = *(const short8*)&Q[bK + (size_t)qrow * NHD + c * 32 + hi * 8];

  short8 vone;
#pragma unroll
  for (int e = 0; e < 8; ++e) vone[e] = (short)0x3F80;   // bf16 1.0

  f32x4 o[4] = {};
  f32x4 o4 = {};          // rowsum accumulator (all 4 regs equal)
  float mr = -INFINITY;   // running row max (exp2 domain), per-lane (q=li)

  issue(0);
  commit(0);
  __syncthreads();
  int buf = 0;

  const int pswz = (li & 7) << 1;   // P-LDS XOR swizzle (8B chunks, bit0 preserved)

  for (int kt = 0; kt <= qb; ++kt) {
    if (kt < qb) issue(kt + 1);    // loads in flight under the compute below

    // S^T = K Q^T : s[g][rg] = S[q=li][k = g*16 + hi*4 + rg]
    f32x4 s[4] = {};
    __builtin_amdgcn_s_setprio(1);
#pragma unroll
    for (int g = 0; g < 4; ++g)
#pragma unroll
      for (int c = 0; c < 2; ++c) {
        short8 kf = *(const short8*)&lK[buf][(g * 16 + li) * 64 + ((c * 4 + hi) ^ (li & 7)) * 8];
        s[g] = __builtin_amdgcn_mfma_f32_16x16x32_bf16(kf, qf[c], s[g], 0, 0, 0);
      }
    __builtin_amdgcn_s_setprio(0);

    if (kt == qb) {                          // causal mask on diagonal tile
#pragma unroll
      for (int g = 0; g < 4; ++g)
#pragma unroll
        for (int rg = 0; rg < 4; ++rg) {
          int kcol = kt * 64 + g * 16 + hi * 4 + rg;
          if (kcol > qrow) s[g][rg] = -INFINITY;
        }
    }

    // tile row max: 15 in-lane fmax + 2 shuffles
    float mg0 = fmaxf(fmaxf(s[0][0], s[0][1]), fmaxf(s[0][2], s[0][3]));
    float mg1 = fmaxf(fmaxf(s[1][0], s[1][1]), fmaxf(s[1][2], s[1][3]));
    float mg2 = fmaxf(fmaxf(s[2][0], s[2][1]), fmaxf(s[2][2], s[2][3]));
    float mg3 = fmaxf(fmaxf(s[3][0], s[3][1]), fmaxf(s[3][2], s[3][3]));
    float pmax = fmaxf(fmaxf(mg0, mg1), fmaxf(mg2, mg3));
    pmax = fmaxf(pmax, __shfl_xor(pmax, 16));
    pmax = fmaxf(pmax, __shfl_xor(pmax, 32));

    // T13 defer-max: only rescale when the tile max exceeds m by > 8 (exp2 domain)
    if (__any(pmax > mr + 8.f)) {
      float mnew = fmaxf(mr, pmax);
      float sc = __builtin_amdgcn_exp2f(mr - mnew);
#pragma unroll
      for (int gd = 0; gd < 4; ++gd)
#pragma unroll
        for (int rg = 0; rg < 4; ++rg) o[gd][rg] *= sc;
#pragma unroll
      for (int rg = 0; rg < 4; ++rg) o4[rg] *= sc;
      mr = mnew;
    }

    // P = exp2(S - m) -> LDS as bf16 (rowsum comes from the MFMA ones-trick)
#pragma unroll
    for (int g = 0; g < 4; ++g) {
      float p0 = __builtin_amdgcn_exp2f(s[g][0] - mr);
      float p1 = __builtin_amdgcn_exp2f(s[g][1] - mr);
      float p2 = __builtin_amdgcn_exp2f(s[g][2] - mr);
      float p3 = __builtin_amdgcn_exp2f(s[g][3] - mr);
      uint2 w;
      w.x = pk2bf(p0, p1);
      w.y = pk2bf(p2, p3);
      int k8s = (g * 4 + hi) ^ pswz;
      *(uint2*)&lP[wid][li * 64 + k8s * 4] = w;
    }

    // P as B-operand: lane reads P[q=li][c*32 + hi*8 .. +7]
    short8 pa[2];
#pragma unroll
    for (int c = 0; c < 2; ++c)
      pa[c] = *(const short8*)&lP[wid][li * 64 + ((c * 8 + hi * 2) ^ pswz) * 4];

    // O^T += V^T P^T ; rowsum via ones
    __builtin_amdgcn_s_setprio(1);
#pragma unroll
    for (int gd = 0; gd < 4; ++gd)
#pragma unroll
      for (int c = 0; c < 2; ++c) {
        short8 vf = *(const short8*)&lVT[buf][(gd * 16 + li) * 64 + ((c * 4 + hi) ^ (li & 7)) * 8];
        o[gd] = __builtin_amdgcn_mfma_f32_16x16x32_bf16(vf, pa[c], o[gd], 0, 0, 0);
      }
#pragma unroll
    for (int c = 0; c < 2; ++c)
      o4 = __builtin_amdgcn_mfma_f32_16x16x32_bf16(vone, pa[c], o4, 0, 0, 0);
    __builtin_amdgcn_s_setprio(0);

    if (kt < qb) commit(buf ^ 1);   // vmcnt consumed here (hidden under compute above)
    __syncthreads();                // vmcnt already 0 -> no drain stall
    buf ^= 1;
  }

  // epilogue: O /= l; pack 4 bf16 (8B) per gd and store
  const int b_ = bh >> 4, h_ = bh & 15;
  const float inv = 1.0f / o4[0];
  const size_t rowbase = ((size_t)(b_ * NT + qrow)) * ND + h_ * 64;
#pragma unroll
  for (int gd = 0; gd < 4; ++gd) {
    uint2 w;
    w.x = pk2bf(o[gd][0] * inv, o[gd][1] * inv);
    w.y = pk2bf(o[gd][2] * inv, o[gd][3] * inv);
    *(uint2*)&AO[rowbase + gd * 16 + hi * 4] = w;
  }
}

// ---------------- RMSNorm in-place on d_out ----------------
__global__ __launch_bounds__(256) void rmsnorm_kernel(float* __restrict__ y,
                                                      const float* __restrict__ g) {
  const int row = blockIdx.x;
  const int tid = threadIdx.x;
  const int lane = tid & 63, wid = tid >> 6;
  float4 v = ((const float4*)(y + (size_t)row * ND))[tid];
  float ss = v.x * v.x + v.y * v.y + v.z * v.z + v.w * v.w;
#pragma unroll
  for (int off = 32; off; off >>= 1) ss += __shfl_down(ss, off);
  __shared__ float red[4];
  if (lane == 0) red[wid] = ss;
  __syncthreads();
  float tot = red[0] + red[1] + red[2] + red[3];
  float inv = rsqrtf(tot * (1.0f / (float)ND) + 1e-6f);
  float4 gg = ((const float4*)g)[tid];
  float4 o;
  o.x = v.x * inv * gg.x; o.y = v.y * inv * gg.y;
  o.z = v.z * inv * gg.z; o.w = v.w * inv * gg.w;
  ((float4*)(y + (size_t)row * ND))[tid] = o;
}

extern "C" void kernel_launch(void* const* d_in, const int* in_sizes, int n_in,
                              void* d_out, int out_size, void* d_ws, size_t ws_size,
                              hipStream_t stream) {
  const float* x  = (const float*)d_in[0];
  const float* wq = (const float*)d_in[1];
  const float* wk = (const float*)d_in[2];
  const float* wv = (const float*)d_in[3];
  const float* wo = (const float*)d_in[4];
  const float* ng = (const float*)d_in[5];
  float* out = (float*)d_out;

  char* ws = (char*)d_ws;
  u16* xb  = (u16*)(ws);                    // 16 MB  [M, D] bf16
  u16* wqb = (u16*)(ws + (16u << 20));      //  2 MB
  u16* wkb = (u16*)(ws + (18u << 20));
  u16* wvb = (u16*)(ws + (20u << 20));
  u16* wob = (u16*)(ws + (22u << 20));
  u16* Qb  = (u16*)(ws + (24u << 20));      // 16 MB  [B,H,T,HD]
  u16* Kb  = (u16*)(ws + (40u << 20));      // 16 MB  [B,H,T,HD]
  u16* VTb = (u16*)(ws + (56u << 20));      // 16 MB  [B,H,HD,T]  (transposed V)
  u16* AO  = (u16*)(ws + (72u << 20));      // 16 MB  [M, D]  (ends at 88 MB)

  cast_kernel<<<NM * ND / 4 / 256, 256, 0, stream>>>(x, xb, NM * ND / 4);
  cast4_kernel<<<4 * 1024, 256, 0, stream>>>(wq, wk, wv, wo, wqb, wkb, wvb, wob);

  gemm_qkv<<<dim3(64, 8, 3), 256, 0, stream>>>(xb, wqb, wkb, wvb, Qb, Kb, VTb);
  attn_kernel<<<dim3(NT / 64, NB * NH), 256, 0, stream>>>(Qb, Kb, VTb, AO);
  gemm_wo<<<dim3(64, 8), 256, 0, stream>>>(AO, wob, x, out);
  rmsnorm_kernel<<<NM, 256, 0, stream>>>(out, ng);
}

// Round 8
// 218.201 us; speedup vs baseline: 1.1904x; 1.0050x over previous
//
#include <hip/hip_runtime.h>
#include <hip/hip_bf16.h>

// Problem constants (B=4, T=2048, D=1024, H=16, HD=64)
constexpr int NB  = 4;
constexpr int NT  = 2048;
constexpr int ND  = 1024;
constexpr int NH  = 16;
constexpr int NHD = 64;
constexpr int NM  = NB * NT;   // 8192 tokens

typedef unsigned short u16;
typedef __attribute__((ext_vector_type(8))) short  short8;  // 8 bf16 (4 VGPRs)
typedef __attribute__((ext_vector_type(4))) float  f32x4;   // MFMA acc

__device__ __forceinline__ u16 f2bf(float f) {
  unsigned u = __builtin_bit_cast(unsigned, f);
  u += 0x7FFFu + ((u >> 16) & 1u);   // round-to-nearest-even
  return (u16)(u >> 16);
}

// pack two f32 -> 2x bf16 in one dword (compiler emits v_cvt_pk_bf16_f32)
__device__ __forceinline__ unsigned pk2bf(float lo, float hi_) {
  float2 t; t.x = lo; t.y = hi_;
  __hip_bfloat162 h2 = __float22bfloat162_rn(t);
  unsigned u;
  __builtin_memcpy(&u, &h2, 4);
  return u;
}

// async global->LDS, 16B per lane. dst must be wave-uniform; lane i lands at dst + i*16B.
__device__ __forceinline__ void gll16(const u16* src, u16* dst) {
  __builtin_amdgcn_global_load_lds(
      (const __attribute__((address_space(1))) void*)src,
      (__attribute__((address_space(3))) void*)dst, 16, 0, 0);
}

// ---------------- cast f32 -> bf16, vectorized x4 ----------------
__global__ __launch_bounds__(256) void cast_kernel(const float* __restrict__ in,
                                                   u16* __restrict__ out, int n4) {
  int i = blockIdx.x * 256 + threadIdx.x;
  if (i >= n4) return;
  float4 v = ((const float4*)in)[i];
  ushort4 o;
  o.x = f2bf(v.x); o.y = f2bf(v.y); o.z = f2bf(v.z); o.w = f2bf(v.w);
  ((ushort4*)out)[i] = o;
}

// cast all 4 weight matrices in one launch (1024 blocks each)
__global__ __launch_bounds__(256) void cast4_kernel(
    const float* __restrict__ w0, const float* __restrict__ w1,
    const float* __restrict__ w2, const float* __restrict__ w3,
    u16* __restrict__ o0, u16* __restrict__ o1,
    u16* __restrict__ o2, u16* __restrict__ o3) {
  const int z = blockIdx.x >> 10;
  const float* in = (z == 0) ? w0 : (z == 1) ? w1 : (z == 2) ? w2 : w3;
  u16* out       = (z == 0) ? o0 : (z == 1) ? o1 : (z == 2) ? o2 : o3;
  int i = (blockIdx.x & 1023) * 256 + threadIdx.x;
  float4 v = ((const float4*)in)[i];
  ushort4 o;
  o.x = f2bf(v.x); o.y = f2bf(v.y); o.z = f2bf(v.z); o.w = f2bf(v.w);
  ((ushort4*)out)[i] = o;
}

// ---------------- QKV GEMM: y = x @ W^T ----------------
// BK=64 tiles ([128][64] u16 = 128B rows), XOR chunk-swizzle staging (conflict-free).
// NATURAL grid mapping (blockIdx.x = row tile): flat%8 = rowTile%8, so all blocks
// sharing an x row-panel land on the same XCD -> x is read ~once per XCD (measured
// r6: 49 MB fetch vs 200 MB with the chunked remap). Do NOT XCD-swizzle this grid.
// Q,K scattered to [B,H,T,HD] (swapped MFMA -> uint2 of 4 d);
// V scattered TRANSPOSED to [B,H,HD,T] (normal -> uint2 of 4 t).
__global__ __launch_bounds__(256) void gemm_qkv(
    const u16* __restrict__ xb,
    const u16* __restrict__ wqb, const u16* __restrict__ wkb, const u16* __restrict__ wvb,
    u16* __restrict__ Qb, u16* __restrict__ Kb, u16* __restrict__ VTb) {
  const int z    = blockIdx.z;
  const int row0 = blockIdx.x << 7;
  const int col0 = blockIdx.y << 7;

  const u16* wsel = (z == 0) ? wqb : (z == 1) ? wkb : wvb;
  u16* osel      = (z == 0) ? Qb  : (z == 1) ? Kb  : VTb;
  // attention scale + log2(e) folded into Q (softmax done in exp2 domain)
  const float scl = (z == 0) ? 0.125f * 1.44269504f : 1.0f;

  const int tid  = threadIdx.x;
  const int lane = tid & 63, wid = tid >> 6;
  const int wm = wid >> 1, wn = wid & 1;
  const int li = lane & 15, hi = lane >> 4;
  const int rl8 = lane >> 3, sl = lane & 7;

  __shared__ __align__(16) u16 lA[128 * 64];
  __shared__ __align__(16) u16 lB[128 * 64];

  f32x4 acc[4][4] = {};

  for (int k0 = 0; k0 < ND; k0 += 64) {
#pragma unroll
    for (int h = 0; h < 4; ++h) {
      int r  = wid * 32 + h * 8 + rl8;
      int cs = ((sl ^ (r & 7)) << 3);
      gll16(&xb  [(size_t)(row0 + r) * ND + k0 + cs], &lA[(wid * 32 + h * 8) * 64]);
      gll16(&wsel[(size_t)(col0 + r) * ND + k0 + cs], &lB[(wid * 32 + h * 8) * 64]);
    }
    __syncthreads();
    short8 a[4][2], b[4][2];
#pragma unroll
    for (int m = 0; m < 4; ++m)
#pragma unroll
      for (int c = 0; c < 2; ++c)
        a[m][c] = *(const short8*)&lA[(wm * 64 + m * 16 + li) * 64 + (((c * 4 + hi) ^ (li & 7)) << 3)];
#pragma unroll
    for (int n = 0; n < 4; ++n)
#pragma unroll
      for (int c = 0; c < 2; ++c)
        b[n][c] = *(const short8*)&lB[(wn * 64 + n * 16 + li) * 64 + (((c * 4 + hi) ^ (li & 7)) << 3)];
    if (z == 2) {
#pragma unroll
      for (int m = 0; m < 4; ++m)
#pragma unroll
        for (int n = 0; n < 4; ++n)
#pragma unroll
          for (int c = 0; c < 2; ++c)
            acc[m][n] = __builtin_amdgcn_mfma_f32_16x16x32_bf16(a[m][c], b[n][c], acc[m][n], 0, 0, 0);
    } else {  // swapped: acc = C^T fragment (row=feature, col=token)
#pragma unroll
      for (int m = 0; m < 4; ++m)
#pragma unroll
        for (int n = 0; n < 4; ++n)
#pragma unroll
          for (int c = 0; c < 2; ++c)
            acc[m][n] = __builtin_amdgcn_mfma_f32_16x16x32_bf16(b[n][c], a[m][c], acc[m][n], 0, 0, 0);
    }
    __syncthreads();
  }

#pragma unroll
  for (int m = 0; m < 4; ++m)
#pragma unroll
    for (int n = 0; n < 4; ++n) {
      if (z == 2) {
        // normal: row=token(hi*4+rg), col=feature(li). Pack 4 consecutive t.
        int token0 = row0 + wm * 64 + m * 16 + hi * 4;
        int col    = col0 + wn * 64 + n * 16 + li;
        int b_ = token0 >> 11, t0 = token0 & (NT - 1);
        int h_ = col >> 6,     d_ = col & (NHD - 1);
        uint2 w;
        w.x = pk2bf(acc[m][n][0], acc[m][n][1]);
        w.y = pk2bf(acc[m][n][2], acc[m][n][3]);
        *(uint2*)&osel[(((size_t)(b_ * NH + h_)) * NHD + d_) * NT + t0] = w;
      } else {
        // swapped: row=feature(hi*4+rg), col=token(li). Pack 4 consecutive d.
        int token = row0 + wm * 64 + m * 16 + li;
        int feat0 = col0 + wn * 64 + n * 16 + hi * 4;
        int b_ = token >> 11, t_ = token & (NT - 1);
        int h_ = feat0 >> 6,  d0 = feat0 & (NHD - 1);
        uint2 w;
        w.x = pk2bf(acc[m][n][0] * scl, acc[m][n][1] * scl);
        w.y = pk2bf(acc[m][n][2] * scl, acc[m][n][3] * scl);
        *(uint2*)&osel[(((size_t)(b_ * NH + h_)) * NT + t_) * NHD + d0] = w;
      }
    }
}

// ---------------- WO GEMM + residual: out = x + AO @ WO^T (f32 out) ----------------
// BK=64 + XOR chunk-swizzle; natural grid mapping (same XCD-clustering argument);
// swapped orientation -> float4 load/store epilogue.
__global__ __launch_bounds__(256) void gemm_wo(
    const u16* __restrict__ ao, const u16* __restrict__ wob,
    const float* __restrict__ x, float* __restrict__ y) {
  const int row0 = blockIdx.x << 7;
  const int col0 = blockIdx.y << 7;

  const int tid  = threadIdx.x;
  const int lane = tid & 63, wid = tid >> 6;
  const int wm = wid >> 1, wn = wid & 1;
  const int li = lane & 15, hi = lane >> 4;
  const int rl8 = lane >> 3, sl = lane & 7;

  __shared__ __align__(16) u16 lA[128 * 64];
  __shared__ __align__(16) u16 lB[128 * 64];

  f32x4 acc[4][4] = {};

  for (int k0 = 0; k0 < ND; k0 += 64) {
#pragma unroll
    for (int h = 0; h < 4; ++h) {
      int r  = wid * 32 + h * 8 + rl8;
      int cs = ((sl ^ (r & 7)) << 3);
      gll16(&ao [(size_t)(row0 + r) * ND + k0 + cs], &lA[(wid * 32 + h * 8) * 64]);
      gll16(&wob[(size_t)(col0 + r) * ND + k0 + cs], &lB[(wid * 32 + h * 8) * 64]);
    }
    __syncthreads();
    short8 a[4][2], b[4][2];
#pragma unroll
    for (int m = 0; m < 4; ++m)
#pragma unroll
      for (int c = 0; c < 2; ++c)
        a[m][c] = *(const short8*)&lA[(wm * 64 + m * 16 + li) * 64 + (((c * 4 + hi) ^ (li & 7)) << 3)];
#pragma unroll
    for (int n = 0; n < 4; ++n)
#pragma unroll
      for (int c = 0; c < 2; ++c)
        b[n][c] = *(const short8*)&lB[(wn * 64 + n * 16 + li) * 64 + (((c * 4 + hi) ^ (li & 7)) << 3)];
#pragma unroll
    for (int m = 0; m < 4; ++m)
#pragma unroll
      for (int n = 0; n < 4; ++n)
#pragma unroll
        for (int c = 0; c < 2; ++c)
          acc[m][n] = __builtin_amdgcn_mfma_f32_16x16x32_bf16(b[n][c], a[m][c], acc[m][n], 0, 0, 0);
    __syncthreads();
  }

#pragma unroll
  for (int m = 0; m < 4; ++m)
#pragma unroll
    for (int n = 0; n < 4; ++n) {
      int token = row0 + wm * 64 + m * 16 + li;
      int feat0 = col0 + wn * 64 + n * 16 + hi * 4;
      size_t idx = (size_t)token * ND + feat0;
      float4 xv = *(const float4*)&x[idx];
      float4 o;
      o.x = acc[m][n][0] + xv.x; o.y = acc[m][n][1] + xv.y;
      o.z = acc[m][n][2] + xv.z; o.w = acc[m][n][3] + xv.w;
      *(float4*)&y[idx] = o;
    }
}

// ---------------- causal flash attention (unchanged from r6/r7) ----------------
__global__ __launch_bounds__(256) void attn_kernel(
    const u16* __restrict__ Q, const u16* __restrict__ K, const u16* __restrict__ VT,
    u16* __restrict__ AO) {
  // T1: XCD-aware swizzle (2048 % 8 == 0 -> bijective)
  const int nb  = gridDim.x * gridDim.y;           // 2048
  const int b0  = blockIdx.y * gridDim.x + blockIdx.x;
  const int L   = (b0 & 7) * (nb >> 3) + (b0 >> 3);
  const int qb  = 31 - (L & 31);     // heavy-first: big qb dispatched early
  const int bh  = L >> 5;            // 0..63

  const int tid = threadIdx.x;
  const int lane = tid & 63, wid = tid >> 6;
  const int li = lane & 15, hi = lane >> 4;
  const int r0 = qb * 64 + wid * 16;         // wave's q rows
  const int qrow = r0 + li;                  // this lane's q row
  const size_t bK = (size_t)bh * NT * NHD;   // K  [bh][t][d]
  const size_t bV = (size_t)bh * NHD * NT;   // VT [bh][d][t]

  __shared__ __align__(16) u16 lK [2][64 * 64];
  __shared__ __align__(16) u16 lVT[2][64 * 64];
  __shared__ __align__(16) u16 lP [4][16 * 64];

  // ---- reg-staging geometry: 512 chunks of 8 u16 per tile; thread owns ch0=tid, ch1=tid+256
  const int ch0 = tid, ch1 = tid + 256;
  // LDS dest (XOR chunk swizzle): row=ch>>3, slot=(ch&7)^(row&7)
  const int d0 = (ch0 >> 3) * 64 + (((ch0 & 7) ^ ((ch0 >> 3) & 7)) << 3);
  const int d1 = (ch1 >> 3) * 64 + (((ch1 & 7) ^ ((ch1 >> 3) & 7)) << 3);
  // K global: chunk ch of tile kt at bK + kt*4096 + ch*8 (contiguous)
  // VT global: row=ch>>3 (d), col8=ch&7 -> bV + (ch>>3)*NT + kt*64 + (ch&7)*8
  const int vOff0 = (ch0 >> 3) * NT + (ch0 & 7) * 8;
  const int vOff1 = (ch1 >> 3) * NT + (ch1 & 7) * 8;

  uint4 gK0, gK1, gV0, gV1;
  auto issue = [&](int kt) {
    const u16* kp = K + bK + (size_t)kt * 4096;
    const u16* vp = VT + bV + kt * 64;
    gK0 = *(const uint4*)&kp[ch0 * 8];
    gK1 = *(const uint4*)&kp[ch1 * 8];
    gV0 = *(const uint4*)&vp[vOff0];
    gV1 = *(const uint4*)&vp[vOff1];
  };
  auto commit = [&](int buf) {
    *(uint4*)&lK [buf][d0] = gK0;
    *(uint4*)&lK [buf][d1] = gK1;
    *(uint4*)&lVT[buf][d0] = gV0;
    *(uint4*)&lVT[buf][d1] = gV1;
  };

  // Q fragments (B-operand): lane holds Q[qrow][c*32 + hi*8 + e]
  short8 qf[2];
#pragma unroll
  for (int c = 0; c < 2; ++c)
    qf[c] = *(const short8*)&Q[bK + (size_t)qrow * NHD + c * 32 + hi * 8];

  short8 vone;
#pragma unroll
  for (int e = 0; e < 8; ++e) vone[e] = (short)0x3F80;   // bf16 1.0

  f32x4 o[4] = {};
  f32x4 o4 = {};          // rowsum accumulator (all 4 regs equal)
  float mr = -INFINITY;   // running row max (exp2 domain), per-lane (q=li)

  issue(0);
  commit(0);
  __syncthreads();
  int buf = 0;

  const int pswz = (li & 7) << 1;   // P-LDS XOR swizzle (8B chunks, bit0 preserved)

  for (int kt = 0; kt <= qb; ++kt) {
    if (kt < qb) issue(kt + 1);    // loads in flight under the compute below

    // S^T = K Q^T : s[g][rg] = S[q=li][k = g*16 + hi*4 + rg]
    f32x4 s[4] = {};
    __builtin_amdgcn_s_setprio(1);
#pragma unroll
    for (int g = 0; g < 4; ++g)
#pragma unroll
      for (int c = 0; c < 2; ++c) {
        short8 kf = *(const short8*)&lK[buf][(g * 16 + li) * 64 + ((c * 4 + hi) ^ (li & 7)) * 8];
        s[g] = __builtin_amdgcn_mfma_f32_16x16x32_bf16(kf, qf[c], s[g], 0, 0, 0);
      }
    __builtin_amdgcn_s_setprio(0);

    if (kt == qb) {                          // causal mask on diagonal tile
#pragma unroll
      for (int g = 0; g < 4; ++g)
#pragma unroll
        for (int rg = 0; rg < 4; ++rg) {
          int kcol = kt * 64 + g * 16 + hi * 4 + rg;
          if (kcol > qrow) s[g][rg] = -INFINITY;
        }
    }

    // tile row max: 15 in-lane fmax + 2 shuffles
    float mg0 = fmaxf(fmaxf(s[0][0], s[0][1]), fmaxf(s[0][2], s[0][3]));
    float mg1 = fmaxf(fmaxf(s[1][0], s[1][1]), fmaxf(s[1][2], s[1][3]));
    float mg2 = fmaxf(fmaxf(s[2][0], s[2][1]), fmaxf(s[2][2], s[2][3]));
    float mg3 = fmaxf(fmaxf(s[3][0], s[3][1]), fmaxf(s[3][2], s[3][3]));
    float pmax = fmaxf(fmaxf(mg0, mg1), fmaxf(mg2, mg3));
    pmax = fmaxf(pmax, __shfl_xor(pmax, 16));
    pmax = fmaxf(pmax, __shfl_xor(pmax, 32));

    // T13 defer-max: only rescale when the tile max exceeds m by > 8 (exp2 domain)
    if (__any(pmax > mr + 8.f)) {
      float mnew = fmaxf(mr, pmax);
      float sc = __builtin_amdgcn_exp2f(mr - mnew);
#pragma unroll
      for (int gd = 0; gd < 4; ++gd)
#pragma unroll
        for (int rg = 0; rg < 4; ++rg) o[gd][rg] *= sc;
#pragma unroll
      for (int rg = 0; rg < 4; ++rg) o4[rg] *= sc;
      mr = mnew;
    }

    // P = exp2(S - m) -> LDS as bf16 (rowsum comes from the MFMA ones-trick)
#pragma unroll
    for (int g = 0; g < 4; ++g) {
      float p0 = __builtin_amdgcn_exp2f(s[g][0] - mr);
      float p1 = __builtin_amdgcn_exp2f(s[g][1] - mr);
      float p2 = __builtin_amdgcn_exp2f(s[g][2] - mr);
      float p3 = __builtin_amdgcn_exp2f(s[g][3] - mr);
      uint2 w;
      w.x = pk2bf(p0, p1);
      w.y = pk2bf(p2, p3);
      int k8s = (g * 4 + hi) ^ pswz;
      *(uint2*)&lP[wid][li * 64 + k8s * 4] = w;
    }

    // P as B-operand: lane reads P[q=li][c*32 + hi*8 .. +7]
    short8 pa[2];
#pragma unroll
    for (int c = 0; c < 2; ++c)
      pa[c] = *(const short8*)&lP[wid][li * 64 + ((c * 8 + hi * 2) ^ pswz) * 4];

    // O^T += V^T P^T ; rowsum via ones
    __builtin_amdgcn_s_setprio(1);
#pragma unroll
    for (int gd = 0; gd < 4; ++gd)
#pragma unroll
      for (int c = 0; c < 2; ++c) {
        short8 vf = *(const short8*)&lVT[buf][(gd * 16 + li) * 64 + ((c * 4 + hi) ^ (li & 7)) * 8];
        o[gd] = __builtin_amdgcn_mfma_f32_16x16x32_bf16(vf, pa[c], o[gd], 0, 0, 0);
      }
#pragma unroll
    for (int c = 0; c < 2; ++c)
      o4 = __builtin_amdgcn_mfma_f32_16x16x32_bf16(vone, pa[c], o4, 0, 0, 0);
    __builtin_amdgcn_s_setprio(0);

    if (kt < qb) commit(buf ^ 1);   // vmcnt consumed here (hidden under compute above)
    __syncthreads();                // vmcnt already 0 -> no drain stall
    buf ^= 1;
  }

  // epilogue: O /= l; pack 4 bf16 (8B) per gd and store
  const int b_ = bh >> 4, h_ = bh & 15;
  const float inv = 1.0f / o4[0];
  const size_t rowbase = ((size_t)(b_ * NT + qrow)) * ND + h_ * 64;
#pragma unroll
  for (int gd = 0; gd < 4; ++gd) {
    uint2 w;
    w.x = pk2bf(o[gd][0] * inv, o[gd][1] * inv);
    w.y = pk2bf(o[gd][2] * inv, o[gd][3] * inv);
    *(uint2*)&AO[rowbase + gd * 16 + hi * 4] = w;
  }
}

// ---------------- RMSNorm in-place on d_out ----------------
__global__ __launch_bounds__(256) void rmsnorm_kernel(float* __restrict__ y,
                                                      const float* __restrict__ g) {
  const int row = blockIdx.x;
  const int tid = threadIdx.x;
  const int lane = tid & 63, wid = tid >> 6;
  float4 v = ((const float4*)(y + (size_t)row * ND))[tid];
  float ss = v.x * v.x + v.y * v.y + v.z * v.z + v.w * v.w;
#pragma unroll
  for (int off = 32; off; off >>= 1) ss += __shfl_down(ss, off);
  __shared__ float red[4];
  if (lane == 0) red[wid] = ss;
  __syncthreads();
  float tot = red[0] + red[1] + red[2] + red[3];
  float inv = rsqrtf(tot * (1.0f / (float)ND) + 1e-6f);
  float4 gg = ((const float4*)g)[tid];
  float4 o;
  o.x = v.x * inv * gg.x; o.y = v.y * inv * gg.y;
  o.z = v.z * inv * gg.z; o.w = v.w * inv * gg.w;
  ((float4*)(y + (size_t)row * ND))[tid] = o;
}

extern "C" void kernel_launch(void* const* d_in, const int* in_sizes, int n_in,
                              void* d_out, int out_size, void* d_ws, size_t ws_size,
                              hipStream_t stream) {
  const float* x  = (const float*)d_in[0];
  const float* wq = (const float*)d_in[1];
  const float* wk = (const float*)d_in[2];
  const float* wv = (const float*)d_in[3];
  const float* wo = (const float*)d_in[4];
  const float* ng = (const float*)d_in[5];
  float* out = (float*)d_out;

  char* ws = (char*)d_ws;
  u16* xb  = (u16*)(ws);                    // 16 MB  [M, D] bf16
  u16* wqb = (u16*)(ws + (16u << 20));      //  2 MB
  u16* wkb = (u16*)(ws + (18u << 20));
  u16* wvb = (u16*)(ws + (20u << 20));
  u16* wob = (u16*)(ws + (22u << 20));
  u16* Qb  = (u16*)(ws + (24u << 20));      // 16 MB  [B,H,T,HD]
  u16* Kb  = (u16*)(ws + (40u << 20));      // 16 MB  [B,H,T,HD]
  u16* VTb = (u16*)(ws + (56u << 20));      // 16 MB  [B,H,HD,T]  (transposed V)
  u16* AO  = (u16*)(ws + (72u << 20));      // 16 MB  [M, D]  (ends at 88 MB)

  cast_kernel<<<NM * ND / 4 / 256, 256, 0, stream>>>(x, xb, NM * ND / 4);
  cast4_kernel<<<4 * 1024, 256, 0, stream>>>(wq, wk, wv, wo, wqb, wkb, wvb, wob);

  gemm_qkv<<<dim3(64, 8, 3), 256, 0, stream>>>(xb, wqb, wkb, wvb, Qb, Kb, VTb);
  attn_kernel<<<dim3(NT / 64, NB * NH), 256, 0, stream>>>(Qb, Kb, VTb, AO);
  gemm_wo<<<dim3(64, 8), 256, 0, stream>>>(AO, wob, x, out);
  rmsnorm_kernel<<<NM, 256, 0, stream>>>(out, ng);
}